// Round 1
// baseline (2022.429 us; speedup 1.0000x reference)
//
#include <hip/hip_runtime.h>
#include <math.h>

// Bahdanau attention, fp32 baseline (correctness-first).
//   B=64, S=4096, H=512
//   d_in: [0]=decoder_hidden (B,H) [1]=encoder_outputs (S,B,H) [2]=W1 (H,H)
//         [3]=W2 (H,H) [4]=v (H)
//   d_out: context (B,H) fp32, then attn_weights (B,S) fp32
//   ws: dp (B*H) | energy (B*S) | pctx (16*B*H)  = 3.125 MiB

#define BATCH 64
#define SEQ   4096
#define HID   512

__device__ __forceinline__ float fast_tanh(float x) {
    // tanh(x) = 1 - 2/(exp(2x)+1); exact at +-inf, rel err ~1e-6
    return 1.0f - 2.0f / (__expf(2.0f * x) + 1.0f);
}

// ---------------------------------------------------------------------------
// K1: dp[b][g] = sum_h dh[b][h] * W1[g][h]
// grid = 512 blocks (one g each), 256 threads: thread = (b = t>>2, q = t&3)
// ---------------------------------------------------------------------------
__global__ void k_decproj(const float* __restrict__ dh,
                          const float* __restrict__ W1,
                          float* __restrict__ dp)
{
    __shared__ float wrow[HID];
    const int g = blockIdx.x;
    const int t = threadIdx.x;
    for (int i = t; i < HID; i += 256) wrow[i] = W1[g * HID + i];
    __syncthreads();

    const int b = t >> 2, q = t & 3;
    const float* dhb = dh + b * HID + q * 128;
    const float* wr  = wrow + q * 128;
    float acc = 0.f;
    #pragma unroll 8
    for (int i = 0; i < 128; i += 4) {
        const float4 d4 = *reinterpret_cast<const float4*>(dhb + i);
        acc = fmaf(d4.x, wr[i + 0], acc);
        acc = fmaf(d4.y, wr[i + 1], acc);
        acc = fmaf(d4.z, wr[i + 2], acc);
        acc = fmaf(d4.w, wr[i + 3], acc);
    }
    acc += __shfl_xor(acc, 1);
    acc += __shfl_xor(acc, 2);
    if (q == 0) dp[b * HID + g] = acc;
}

// ---------------------------------------------------------------------------
// K2: energy[b][s] = sum_g tanh(dp[b][g] + sum_h enc[s][b][h]*W2[g][h]) * v[g]
// grid = (64 s-chunks, 64 b), block = 512 threads (8 waves).
// Block tile: 64 s  x  512 g (full), K staged in chunks of 16.
// Thread (tx = t&15 -> 4 s-rows, ty = t>>4 in [0,32) -> 16 g-cols).
// LDS: As[64][17] (pad 17: read bank = (4tx+17j+k)%32, 2-way max)
//      Bs[16][516] (pad 516: b128-aligned, 2-way max)
// ---------------------------------------------------------------------------
__global__ __launch_bounds__(512, 2)
void k_energy(const float* __restrict__ enc, const float* __restrict__ W2,
              const float* __restrict__ dp,  const float* __restrict__ v,
              float* __restrict__ energy)
{
    __shared__ float As[64][17];
    __shared__ float Bs[16][516];
    __shared__ float part[32][64];

    const int chunk = blockIdx.x;
    const int b     = blockIdx.y;
    const int t     = threadIdx.x;
    const int tx    = t & 15;
    const int ty    = t >> 4;
    const int s0    = chunk * 64;

    float acc[4][16];
    #pragma unroll
    for (int j = 0; j < 4; ++j)
        #pragma unroll
        for (int i = 0; i < 16; ++i) acc[j][i] = 0.f;

    for (int kb = 0; kb < 32; ++kb) {
        const int k0 = kb * 16;
        // stage A tile: 64 s x 16 k (1024 floats, threads 0..255, one float4 each)
        if (t < 256) {
            const int s = t >> 2, q = t & 3;
            const float4 f = *reinterpret_cast<const float4*>(
                enc + ((size_t)(s0 + s) * BATCH + b) * HID + k0 + q * 4);
            As[s][q * 4 + 0] = f.x;  As[s][q * 4 + 1] = f.y;
            As[s][q * 4 + 2] = f.z;  As[s][q * 4 + 3] = f.w;
        }
        // stage B tile: Bs[k][g] = W2[g][k0+k]  (8192 floats, 4 float4/thread)
        #pragma unroll
        for (int it = 0; it < 4; ++it) {
            const int idx = t + it * 512;          // float4 index, 0..2047
            const int g = idx >> 2, kq = idx & 3;
            const float4 f = *reinterpret_cast<const float4*>(
                W2 + (size_t)g * HID + k0 + kq * 4);
            Bs[kq * 4 + 0][g] = f.x;  Bs[kq * 4 + 1][g] = f.y;
            Bs[kq * 4 + 2][g] = f.z;  Bs[kq * 4 + 3][g] = f.w;
        }
        __syncthreads();

        #pragma unroll
        for (int k = 0; k < 16; ++k) {
            const float a0 = As[tx * 4 + 0][k];
            const float a1 = As[tx * 4 + 1][k];
            const float a2 = As[tx * 4 + 2][k];
            const float a3 = As[tx * 4 + 3][k];
            const float4 b0 = *reinterpret_cast<const float4*>(&Bs[k][ty * 16 + 0]);
            const float4 b1 = *reinterpret_cast<const float4*>(&Bs[k][ty * 16 + 4]);
            const float4 b2 = *reinterpret_cast<const float4*>(&Bs[k][ty * 16 + 8]);
            const float4 b3 = *reinterpret_cast<const float4*>(&Bs[k][ty * 16 + 12]);
            const float bb[16] = { b0.x, b0.y, b0.z, b0.w,  b1.x, b1.y, b1.z, b1.w,
                                   b2.x, b2.y, b2.z, b2.w,  b3.x, b3.y, b3.z, b3.w };
            #pragma unroll
            for (int i = 0; i < 16; ++i) {
                acc[0][i] = fmaf(a0, bb[i], acc[0][i]);
                acc[1][i] = fmaf(a1, bb[i], acc[1][i]);
                acc[2][i] = fmaf(a2, bb[i], acc[2][i]);
                acc[3][i] = fmaf(a3, bb[i], acc[3][i]);
            }
        }
        __syncthreads();
    }

    // epilogue: tanh(dp+c)*v, reduce over this thread's 16 g
    float ep0 = 0.f, ep1 = 0.f, ep2 = 0.f, ep3 = 0.f;
    const int gbase = ty * 16;
    #pragma unroll
    for (int i = 0; i < 16; ++i) {
        const float dv = dp[b * HID + gbase + i];
        const float vv = v[gbase + i];
        ep0 += fast_tanh(dv + acc[0][i]) * vv;
        ep1 += fast_tanh(dv + acc[1][i]) * vv;
        ep2 += fast_tanh(dv + acc[2][i]) * vv;
        ep3 += fast_tanh(dv + acc[3][i]) * vv;
    }
    part[ty][tx * 4 + 0] = ep0;
    part[ty][tx * 4 + 1] = ep1;
    part[ty][tx * 4 + 2] = ep2;
    part[ty][tx * 4 + 3] = ep3;
    __syncthreads();

    if (t < 64) {
        float e = 0.f;
        #pragma unroll
        for (int w = 0; w < 32; ++w) e += part[w][t];
        energy[(size_t)b * SEQ + s0 + t] = e;
    }
}

// ---------------------------------------------------------------------------
// K3: softmax over s per b. grid = 64 blocks, 256 threads, 16 elems/thread.
// ---------------------------------------------------------------------------
__global__ void k_softmax(const float* __restrict__ energy,
                          float* __restrict__ attn)
{
    __shared__ float redm[4], reds[4];
    const int b = blockIdx.x, t = threadIdx.x;
    const float* e = energy + (size_t)b * SEQ;

    float4 ev[4];
    float m = -3.4e38f;
    #pragma unroll
    for (int i = 0; i < 4; ++i) {
        ev[i] = *reinterpret_cast<const float4*>(e + i * 1024 + t * 4);
        m = fmaxf(m, fmaxf(fmaxf(ev[i].x, ev[i].y), fmaxf(ev[i].z, ev[i].w)));
    }
    #pragma unroll
    for (int off = 1; off < 64; off <<= 1) m = fmaxf(m, __shfl_xor(m, off));
    if ((t & 63) == 0) redm[t >> 6] = m;
    __syncthreads();
    m = fmaxf(fmaxf(redm[0], redm[1]), fmaxf(redm[2], redm[3]));

    float s = 0.f;
    #pragma unroll
    for (int i = 0; i < 4; ++i) {
        ev[i].x = __expf(ev[i].x - m);  ev[i].y = __expf(ev[i].y - m);
        ev[i].z = __expf(ev[i].z - m);  ev[i].w = __expf(ev[i].w - m);
        s += (ev[i].x + ev[i].y) + (ev[i].z + ev[i].w);
    }
    #pragma unroll
    for (int off = 1; off < 64; off <<= 1) s += __shfl_xor(s, off);
    if ((t & 63) == 0) reds[t >> 6] = s;
    __syncthreads();
    s = (reds[0] + reds[1]) + (reds[2] + reds[3]);
    const float inv = 1.0f / s;

    float* o = attn + (size_t)b * SEQ;
    #pragma unroll
    for (int i = 0; i < 4; ++i) {
        const float4 w4 = make_float4(ev[i].x * inv, ev[i].y * inv,
                                      ev[i].z * inv, ev[i].w * inv);
        *reinterpret_cast<float4*>(o + i * 1024 + t * 4) = w4;
    }
}

// ---------------------------------------------------------------------------
// K4: partial context. grid = (64 b, 16 s-splits), 256 threads.
// Thread handles h = {2t, 2t+1} via float2; 256 s per block.
// ---------------------------------------------------------------------------
__global__ void k_ctxpart(const float* __restrict__ enc,
                          const float* __restrict__ attn,
                          float* __restrict__ pctx)
{
    __shared__ float w[256];
    const int b  = blockIdx.x;
    const int sp = blockIdx.y;
    const int t  = threadIdx.x;

    w[t] = attn[(size_t)b * SEQ + sp * 256 + t];
    __syncthreads();

    const float2* e2 = reinterpret_cast<const float2*>(enc);
    size_t idx = ((size_t)sp * 256 * BATCH + b) * (HID / 2) + t;
    const size_t stride = (size_t)BATCH * (HID / 2);     // per-s step in float2

    float ax = 0.f, ay = 0.f;
    #pragma unroll 4
    for (int s = 0; s < 256; ++s) {
        const float2 ev = e2[idx];
        const float ws = w[s];
        ax = fmaf(ws, ev.x, ax);
        ay = fmaf(ws, ev.y, ay);
        idx += stride;
    }
    float2* p2 = reinterpret_cast<float2*>(pctx);
    p2[((size_t)sp * BATCH + b) * (HID / 2) + t] = make_float2(ax, ay);
}

// ---------------------------------------------------------------------------
// K5: context[b][h] = sum over 16 splits. grid = 128 blocks, 256 threads.
// ---------------------------------------------------------------------------
__global__ void k_ctxsum(const float* __restrict__ pctx,
                         float* __restrict__ ctx)
{
    const int i = blockIdx.x * 256 + threadIdx.x;   // 0..32767
    float s = 0.f;
    #pragma unroll
    for (int sp = 0; sp < 16; ++sp) s += pctx[(size_t)sp * BATCH * HID + i];
    ctx[i] = s;
}

// ---------------------------------------------------------------------------
extern "C" void kernel_launch(void* const* d_in, const int* in_sizes, int n_in,
                              void* d_out, int out_size, void* d_ws, size_t ws_size,
                              hipStream_t stream)
{
    const float* dh  = (const float*)d_in[0];   // (64, 512)
    const float* enc = (const float*)d_in[1];   // (4096, 64, 512)
    const float* W1  = (const float*)d_in[2];   // (512, 512)
    const float* W2  = (const float*)d_in[3];   // (512, 512)
    const float* v   = (const float*)d_in[4];   // (512,)

    float* out  = (float*)d_out;
    float* ctx  = out;                           // 64*512
    float* attn = out + BATCH * HID;             // 64*4096

    float* dp     = (float*)d_ws;                // 32768 f
    float* energy = dp + BATCH * HID;            // 262144 f
    float* pctx   = energy + (size_t)BATCH * SEQ;// 16*64*512 f

    k_decproj<<<HID, 256, 0, stream>>>(dh, W1, dp);
    k_energy <<<dim3(SEQ / 64, BATCH), 512, 0, stream>>>(enc, W2, dp, v, energy);
    k_softmax<<<BATCH, 256, 0, stream>>>(energy, attn);
    k_ctxpart<<<dim3(BATCH, 16), 256, 0, stream>>>(enc, attn, pctx);
    k_ctxsum <<<BATCH * HID / 256, 256, 0, stream>>>(pctx, ctx);
}

// Round 2
// 420.524 us; speedup vs baseline: 4.8093x; 4.8093x over previous
//
#include <hip/hip_runtime.h>
#include <math.h>

// Bahdanau attention, round 1: bf16-MFMA energy GEMM.
//   B=64, S=4096, H=512, all fp32 in/out.
//   d_in: [0]=decoder_hidden (B,H) [1]=encoder_outputs (S,B,H) [2]=W1 (H,H)
//         [3]=W2 (H,H) [4]=v (H)
//   d_out: context (B,H) fp32, then attn_weights (B,S) fp32
//   ws: dp (B*H f32) | W2bf (H*H ushort) | pctx (16*B*H f32) = 2.625 MiB
//   energy is written into d_out's attn region; softmax runs in place there.

#define BATCH 64
#define SEQ   4096
#define HID   512

typedef __attribute__((ext_vector_type(8))) short bf16x8;
typedef __attribute__((ext_vector_type(4))) float f32x4;

__device__ __forceinline__ float fast_tanh(float x) {
    // tanh(x) = 1 - 2/(exp(2x)+1); exact at +-inf, rel err ~1e-6
    return 1.0f - 2.0f / (__expf(2.0f * x) + 1.0f);
}

__device__ __forceinline__ ushort f2bf(float x) {
    union { float f; unsigned u; } c; c.f = x;
    const unsigned r = c.u + 0x7FFFu + ((c.u >> 16) & 1u);   // RNE
    return (ushort)(r >> 16);
}

// ---------------------------------------------------------------------------
// K0: W2 fp32 -> bf16 (ushort) into ws. 256 blocks x 256 thr, 4 elems/thr.
// ---------------------------------------------------------------------------
__global__ void k_cvtW2(const float* __restrict__ W2, ushort* __restrict__ W2bf)
{
    const int i = (blockIdx.x * 256 + threadIdx.x) * 4;
    const float4 f = *reinterpret_cast<const float4*>(W2 + i);
    ushort4 u;
    u.x = f2bf(f.x); u.y = f2bf(f.y); u.z = f2bf(f.z); u.w = f2bf(f.w);
    *reinterpret_cast<ushort4*>(W2bf + i) = u;
}

// ---------------------------------------------------------------------------
// K1: dp[b][g] = sum_h dh[b][h] * W1[g][h]  (fp32, tiny)
// grid = 512 blocks (one g each), 256 threads: thread = (b = t>>2, q = t&3)
// ---------------------------------------------------------------------------
__global__ void k_decproj(const float* __restrict__ dh,
                          const float* __restrict__ W1,
                          float* __restrict__ dp)
{
    __shared__ float wrow[HID];
    const int g = blockIdx.x;
    const int t = threadIdx.x;
    for (int i = t; i < HID; i += 256) wrow[i] = W1[g * HID + i];
    __syncthreads();

    const int b = t >> 2, q = t & 3;
    const float* dhb = dh + b * HID + q * 128;
    const float* wr  = wrow + q * 128;
    float acc = 0.f;
    #pragma unroll 8
    for (int i = 0; i < 128; i += 4) {
        const float4 d4 = *reinterpret_cast<const float4*>(dhb + i);
        acc = fmaf(d4.x, wr[i + 0], acc);
        acc = fmaf(d4.y, wr[i + 1], acc);
        acc = fmaf(d4.z, wr[i + 2], acc);
        acc = fmaf(d4.w, wr[i + 3], acc);
    }
    acc += __shfl_xor(acc, 1);
    acc += __shfl_xor(acc, 2);
    if (q == 0) dp[b * HID + g] = acc;
}

// ---------------------------------------------------------------------------
// K2: energy[b][s] = sum_g tanh(dp[b][g] + sum_h enc[s][b][h]*W2[g][h]) * v[g]
// bf16 MFMA version. grid = (64 s-chunks, 64 b), block = 512 threads (8 waves).
// Block tile: 64 s x 512 g (full g), K staged at BK=32.
// Wave w owns g in [w*64, w*64+64): 4x4 tiles of 16x16 MFMA output.
// LDS rows padded to 40 ushorts (80 B = 5 x 16B slots -> 2-way max on b128).
// Fragment layout (mfma_f32_16x16x32_bf16):
//   A: lane l holds A[row = l&15][k = (l>>4)*8 + j], j=0..7 (8 contiguous k)
//   B: lane l holds B[k = (l>>4)*8 + j][col = l&15]
//   C: lane l, reg r -> row = (l>>4)*4 + r, col = l&15   [m89-verified]
// ---------------------------------------------------------------------------
#define BK    32
#define LDA   40   // ushorts per row (80 B)

__global__ __launch_bounds__(512, 4)
void k_energy(const float* __restrict__ enc, const ushort* __restrict__ W2bf,
              const float* __restrict__ dp,  const float* __restrict__ v,
              float* __restrict__ energy)
{
    __shared__ ushort As[64 * LDA];        //  5 KiB
    __shared__ ushort Bs[512 * LDA];       // 40 KiB
    __shared__ float  part[8][64];         //  2 KiB

    const int chunk = blockIdx.x;
    const int b     = blockIdx.y;
    const int t     = threadIdx.x;
    const int s0    = chunk * 64;
    const int lane  = t & 63;
    const int wv    = t >> 6;              // wave id 0..7 -> g block
    const int gl    = lane & 15;
    const int rg    = lane >> 4;           // 0..3 (k-slot / row-group)

    f32x4 acc[4][4];
    const f32x4 z = {0.f, 0.f, 0.f, 0.f};
    #pragma unroll
    for (int m = 0; m < 4; ++m)
        #pragma unroll
        for (int n = 0; n < 4; ++n) acc[m][n] = z;

    const int arow = t >> 3, ack = t & 7;  // A staging: row 0..63, k-chunk 0..7
    const float* aptr = enc + ((size_t)(s0 + arow) * BATCH + b) * HID + ack * 4;

    for (int kb = 0; kb < 16; ++kb) {
        const int k0 = kb * BK;
        // stage A: 64 s x 32 k fp32 -> bf16 (one float4 per thread)
        {
            const float4 f = *reinterpret_cast<const float4*>(aptr + k0);
            ushort4 u;
            u.x = f2bf(f.x); u.y = f2bf(f.y); u.z = f2bf(f.z); u.w = f2bf(f.w);
            *reinterpret_cast<ushort4*>(&As[arow * LDA + ack * 4]) = u;
        }
        // stage B: 512 g x 32 k bf16 (4 x 16B per thread, from L2-resident W2bf)
        #pragma unroll
        for (int it = 0; it < 4; ++it) {
            const int idx = t + it * 512;          // 16B-chunk index, 0..2047
            const int g = idx >> 2, sl = idx & 3;
            const uint4 w4 = *reinterpret_cast<const uint4*>(
                W2bf + (size_t)g * HID + k0 + sl * 8);
            *reinterpret_cast<uint4*>(&Bs[g * LDA + sl * 8]) = w4;
        }
        __syncthreads();

        bf16x8 af[4], bf[4];
        #pragma unroll
        for (int m = 0; m < 4; ++m)
            af[m] = *reinterpret_cast<const bf16x8*>(&As[(m * 16 + gl) * LDA + rg * 8]);
        #pragma unroll
        for (int n = 0; n < 4; ++n)
            bf[n] = *reinterpret_cast<const bf16x8*>(&Bs[(wv * 64 + n * 16 + gl) * LDA + rg * 8]);
        #pragma unroll
        for (int m = 0; m < 4; ++m)
            #pragma unroll
            for (int n = 0; n < 4; ++n)
                acc[m][n] = __builtin_amdgcn_mfma_f32_16x16x32_bf16(
                    af[m], bf[n], acc[m][n], 0, 0, 0);
        __syncthreads();
    }

    // epilogue: p[s-part] = sum over lane's g of tanh(dp+c)*v
    float dpv[4], vv[4];
    #pragma unroll
    for (int n = 0; n < 4; ++n) {
        const int g = wv * 64 + n * 16 + gl;
        dpv[n] = dp[b * HID + g];
        vv[n]  = v[g];
    }
    float p[4][4];                          // [m][reg]
    #pragma unroll
    for (int m = 0; m < 4; ++m)
        #pragma unroll
        for (int r = 0; r < 4; ++r) p[m][r] = 0.f;
    #pragma unroll
    for (int n = 0; n < 4; ++n)
        #pragma unroll
        for (int m = 0; m < 4; ++m)
            #pragma unroll
            for (int r = 0; r < 4; ++r)
                p[m][r] += fast_tanh(dpv[n] + acc[m][n][r]) * vv[n];

    #pragma unroll
    for (int m = 0; m < 4; ++m)
        #pragma unroll
        for (int r = 0; r < 4; ++r) {
            float x = p[m][r];
            x += __shfl_xor(x, 1);
            x += __shfl_xor(x, 2);
            x += __shfl_xor(x, 4);
            x += __shfl_xor(x, 8);
            p[m][r] = x;
        }
    if (gl == 0) {
        #pragma unroll
        for (int m = 0; m < 4; ++m)
            #pragma unroll
            for (int r = 0; r < 4; ++r)
                part[wv][m * 16 + rg * 4 + r] = p[m][r];
    }
    __syncthreads();

    if (t < 64) {
        float e = 0.f;
        #pragma unroll
        for (int w = 0; w < 8; ++w) e += part[w][t];
        energy[(size_t)b * SEQ + s0 + t] = e;
    }
}

// ---------------------------------------------------------------------------
// K3: softmax over s per b, IN PLACE on the attn region of d_out.
// grid = 64 blocks, 256 threads, 16 elems/thread.
// ---------------------------------------------------------------------------
__global__ void k_softmax(float* __restrict__ attn)
{
    __shared__ float redm[4], reds[4];
    const int b = blockIdx.x, t = threadIdx.x;
    float* e = attn + (size_t)b * SEQ;

    float4 ev[4];
    float m = -3.4e38f;
    #pragma unroll
    for (int i = 0; i < 4; ++i) {
        ev[i] = *reinterpret_cast<const float4*>(e + i * 1024 + t * 4);
        m = fmaxf(m, fmaxf(fmaxf(ev[i].x, ev[i].y), fmaxf(ev[i].z, ev[i].w)));
    }
    #pragma unroll
    for (int off = 1; off < 64; off <<= 1) m = fmaxf(m, __shfl_xor(m, off));
    if ((t & 63) == 0) redm[t >> 6] = m;
    __syncthreads();
    m = fmaxf(fmaxf(redm[0], redm[1]), fmaxf(redm[2], redm[3]));

    float s = 0.f;
    #pragma unroll
    for (int i = 0; i < 4; ++i) {
        ev[i].x = __expf(ev[i].x - m);  ev[i].y = __expf(ev[i].y - m);
        ev[i].z = __expf(ev[i].z - m);  ev[i].w = __expf(ev[i].w - m);
        s += (ev[i].x + ev[i].y) + (ev[i].z + ev[i].w);
    }
    #pragma unroll
    for (int off = 1; off < 64; off <<= 1) s += __shfl_xor(s, off);
    if ((t & 63) == 0) reds[t >> 6] = s;
    __syncthreads();
    s = (reds[0] + reds[1]) + (reds[2] + reds[3]);
    const float inv = 1.0f / s;

    #pragma unroll
    for (int i = 0; i < 4; ++i) {
        const float4 w4 = make_float4(ev[i].x * inv, ev[i].y * inv,
                                      ev[i].z * inv, ev[i].w * inv);
        *reinterpret_cast<float4*>(e + i * 1024 + t * 4) = w4;
    }
}

// ---------------------------------------------------------------------------
// K4: partial context. grid = (64 b, 16 s-splits), 256 threads.
// Thread handles h = {2t, 2t+1} via float2; 256 s per block.
// ---------------------------------------------------------------------------
__global__ void k_ctxpart(const float* __restrict__ enc,
                          const float* __restrict__ attn,
                          float* __restrict__ pctx)
{
    __shared__ float w[256];
    const int b  = blockIdx.x;
    const int sp = blockIdx.y;
    const int t  = threadIdx.x;

    w[t] = attn[(size_t)b * SEQ + sp * 256 + t];
    __syncthreads();

    const float2* e2 = reinterpret_cast<const float2*>(enc);
    size_t idx = ((size_t)sp * 256 * BATCH + b) * (HID / 2) + t;
    const size_t stride = (size_t)BATCH * (HID / 2);

    float ax = 0.f, ay = 0.f;
    #pragma unroll 4
    for (int s = 0; s < 256; ++s) {
        const float2 ev = e2[idx];
        const float ws = w[s];
        ax = fmaf(ws, ev.x, ax);
        ay = fmaf(ws, ev.y, ay);
        idx += stride;
    }
    float2* p2 = reinterpret_cast<float2*>(pctx);
    p2[((size_t)sp * BATCH + b) * (HID / 2) + t] = make_float2(ax, ay);
}

// ---------------------------------------------------------------------------
// K5: context[b][h] = sum over 16 splits. grid = 128 blocks, 256 threads.
// ---------------------------------------------------------------------------
__global__ void k_ctxsum(const float* __restrict__ pctx,
                         float* __restrict__ ctx)
{
    const int i = blockIdx.x * 256 + threadIdx.x;   // 0..32767
    float s = 0.f;
    #pragma unroll
    for (int sp = 0; sp < 16; ++sp) s += pctx[(size_t)sp * BATCH * HID + i];
    ctx[i] = s;
}

// ---------------------------------------------------------------------------
extern "C" void kernel_launch(void* const* d_in, const int* in_sizes, int n_in,
                              void* d_out, int out_size, void* d_ws, size_t ws_size,
                              hipStream_t stream)
{
    const float* dh  = (const float*)d_in[0];   // (64, 512)
    const float* enc = (const float*)d_in[1];   // (4096, 64, 512)
    const float* W1  = (const float*)d_in[2];   // (512, 512)
    const float* W2  = (const float*)d_in[3];   // (512, 512)
    const float* v   = (const float*)d_in[4];   // (512,)

    float* out  = (float*)d_out;
    float* ctx  = out;                           // 64*512
    float* attn = out + BATCH * HID;             // 64*4096 (energy -> softmax in place)

    float*  dp   = (float*)d_ws;                         // 32768 f   (128 KiB)
    ushort* W2bf = (ushort*)(dp + BATCH * HID);          // 262144 u16 (512 KiB)
    float*  pctx = (float*)(W2bf + HID * HID);           // 16*64*512 f (2 MiB)

    k_cvtW2  <<<256, 256, 0, stream>>>(W2, W2bf);
    k_decproj<<<HID, 256, 0, stream>>>(dh, W1, dp);
    k_energy <<<dim3(SEQ / 64, BATCH), 512, 0, stream>>>(enc, W2bf, dp, v, attn);
    k_softmax<<<BATCH, 256, 0, stream>>>(attn);
    k_ctxpart<<<dim3(BATCH, 16), 256, 0, stream>>>(enc, attn, pctx);
    k_ctxsum <<<BATCH * HID / 256, 256, 0, stream>>>(pctx, ctx);
}

// Round 3
// 393.968 us; speedup vs baseline: 5.1335x; 1.0674x over previous
//
#include <hip/hip_runtime.h>
#include <math.h>

// Bahdanau attention, round 2: glds-B + double-buffer + A-prefetch energy GEMM.
//   B=64, S=4096, H=512, all fp32 in/out.
//   ws: dp (B*H f32) | W2t (H*H bf16, K-step-tiled + XOR-swizzled) | pctx = 2.625 MiB
//   energy lives in d_out's attn region; softmax in place.

#define BATCH 64
#define SEQ   4096
#define HID   512

typedef __attribute__((ext_vector_type(8))) short bf16x8;
typedef __attribute__((ext_vector_type(4))) float f32x4;

__device__ __forceinline__ float fast_tanh(float x) {
    // tanh(x) = 1 - 2/(exp(2x)+1); exact at +-inf, rel err ~1e-6
    return 1.0f - 2.0f / (__expf(2.0f * x) + 1.0f);
}

__device__ __forceinline__ unsigned cvt2(float lo, float hi) {
    unsigned r;
    asm("v_cvt_pk_bf16_f32 %0, %1, %2" : "=v"(r) : "v"(lo), "v"(hi));
    return r;
}

__device__ __forceinline__ void gload_lds16(const void* g, void* l) {
    __builtin_amdgcn_global_load_lds(
        (const __attribute__((address_space(1))) unsigned*)g,
        (__attribute__((address_space(3))) unsigned*)l, 16, 0, 0);
}

// ---------------------------------------------------------------------------
// K0: W2 fp32 -> bf16, rearranged into K-step-tiled fragment order with the
// LDS XOR swizzle PRE-APPLIED (glds writes LDS linearly; reads apply the same
// XOR). Per K-step kb (BK=32): 16B slot f = g*4 + rg holds
// W2[g][kb*32 + rg*8 .. +7]; stored at slot f ^ ((f>>3)&7)  (bijective).
// grid = 128 x 256 thr; thread n -> (kb = n>>11, f = n&2047).
// ---------------------------------------------------------------------------
__global__ void k_cvtW2(const float* __restrict__ W2, ushort* __restrict__ W2t)
{
    const int n  = blockIdx.x * 256 + threadIdx.x;   // 0..32767
    const int kb = n >> 11;
    const int f  = n & 2047;
    const int g  = f >> 2, rg = f & 3;
    const float* src = W2 + (size_t)g * HID + kb * 32 + rg * 8;
    const float4 x = *reinterpret_cast<const float4*>(src);
    const float4 y = *reinterpret_cast<const float4*>(src + 4);
    uint4 u;
    u.x = cvt2(x.x, x.y);  u.y = cvt2(x.z, x.w);
    u.z = cvt2(y.x, y.y);  u.w = cvt2(y.z, y.w);
    const int slot = f ^ ((f >> 3) & 7);
    *reinterpret_cast<uint4*>(W2t + (size_t)kb * 16384 + slot * 8) = u;
}

// ---------------------------------------------------------------------------
// K1: dp[b][g] = sum_h dh[b][h] * W1[g][h]  (fp32, tiny)
// ---------------------------------------------------------------------------
__global__ void k_decproj(const float* __restrict__ dh,
                          const float* __restrict__ W1,
                          float* __restrict__ dp)
{
    __shared__ float wrow[HID];
    const int g = blockIdx.x;
    const int t = threadIdx.x;
    for (int i = t; i < HID; i += 256) wrow[i] = W1[g * HID + i];
    __syncthreads();

    const int b = t >> 2, q = t & 3;
    const float* dhb = dh + b * HID + q * 128;
    const float* wr  = wrow + q * 128;
    float acc = 0.f;
    #pragma unroll 8
    for (int i = 0; i < 128; i += 4) {
        const float4 d4 = *reinterpret_cast<const float4*>(dhb + i);
        acc = fmaf(d4.x, wr[i + 0], acc);
        acc = fmaf(d4.y, wr[i + 1], acc);
        acc = fmaf(d4.z, wr[i + 2], acc);
        acc = fmaf(d4.w, wr[i + 3], acc);
    }
    acc += __shfl_xor(acc, 1);
    acc += __shfl_xor(acc, 2);
    if (q == 0) dp[b * HID + g] = acc;
}

// ---------------------------------------------------------------------------
// K2: energy[b][s] = sum_g tanh(dp[b][g] + sum_h enc[s][b][h]*W2[g][h]) * v[g]
// grid = (32 s-chunks, 64 b), 512 thr (8 waves as 2M x 4N).
// Block tile 128s x 512g, BK=32, 16 K-steps.
// Wave tile 64s x 128g = 4 x 8 fragments of 16x16x32 MFMA.
// A: reg-prefetched (fp32->bf16 cvt_pk), LDS rows padded to 40 u16 (2-way max).
// B: global_load_lds from pre-swizzled W2t, double-buffered (latency hidden
//    under MFMA; vmcnt drain at next barrier).
// ---------------------------------------------------------------------------
#define LDA 40

__global__ __launch_bounds__(512, 2)
void k_energy(const float* __restrict__ enc, const ushort* __restrict__ W2t,
              const float* __restrict__ dp,  const float* __restrict__ v,
              float* __restrict__ energy)
{
    __shared__ __align__(16) ushort As[128 * LDA];     // 10 KiB
    __shared__ __align__(16) ushort Bs[2][16384];      // 2 x 32 KiB
    __shared__ float part[8][64];                      //  2 KiB

    const int b    = blockIdx.y;
    const int s0   = blockIdx.x * 128;
    const int t    = threadIdx.x;
    const int lane = t & 63;
    const int wv   = t >> 6;
    const int wm   = wv >> 2, wn = wv & 3;
    const int gl   = lane & 15, rg = lane >> 4;

    f32x4 acc[4][8];
    const f32x4 z = {0.f, 0.f, 0.f, 0.f};
    #pragma unroll
    for (int m = 0; m < 4; ++m)
        #pragma unroll
        for (int n = 0; n < 8; ++n) acc[m][n] = z;

    // A staging: thread -> (row = t>>2 in [0,128), kq = t&3), 8 floats/step
    const int arow = t >> 2, akq = t & 3;
    const float* aptr = enc + ((size_t)(s0 + arow) * BATCH + b) * HID + akq * 8;

    // fragment offsets (ushort indices)
    int aoff[4];
    #pragma unroll
    for (int m = 0; m < 4; ++m)
        aoff[m] = (wm * 64 + m * 16 + gl) * LDA + rg * 8;
    int boff[8];
    #pragma unroll
    for (int n = 0; n < 8; ++n) {
        const int g = wn * 128 + n * 16 + gl;
        const int f = g * 4 + rg;
        boff[n] = (f ^ ((f >> 3) & 7)) * 8;
    }

    // prologue: glds B(0) into buf0; prefetch A(0) into regs
    const char* wsrc = (const char*)W2t;
    #pragma unroll
    for (int r = 0; r < 4; ++r)
        gload_lds16(wsrc + (r * 512 + t) * 16, (char*)&Bs[0][0] + (r * 512 + t) * 16);
    float4 a0 = *reinterpret_cast<const float4*>(aptr);
    float4 a1 = *reinterpret_cast<const float4*>(aptr + 4);

    for (int kb = 0; kb < 16; ++kb) {
        __syncthreads();                    // (a) prev-step LDS reads done (+ drains in-flight vmem)
        {   // write As(kb) from prefetched regs
            uint4 aw;
            aw.x = cvt2(a0.x, a0.y);  aw.y = cvt2(a0.z, a0.w);
            aw.z = cvt2(a1.x, a1.y);  aw.w = cvt2(a1.z, a1.w);
            *reinterpret_cast<uint4*>(&As[arow * LDA + akq * 8]) = aw;
        }
        __syncthreads();                    // (b) As(kb) + glds(kb) visible

        const int cur = kb & 1;
        if (kb < 15) {                      // issue next-step staging; hides under MFMA
            const char* src = wsrc + (size_t)(kb + 1) * 32768;
            #pragma unroll
            for (int r = 0; r < 4; ++r)
                gload_lds16(src + (r * 512 + t) * 16,
                            (char*)&Bs[cur ^ 1][0] + (r * 512 + t) * 16);
            a0 = *reinterpret_cast<const float4*>(aptr + (kb + 1) * 32);
            a1 = *reinterpret_cast<const float4*>(aptr + (kb + 1) * 32 + 4);
        }

        bf16x8 af[4], bf[8];
        #pragma unroll
        for (int m = 0; m < 4; ++m)
            af[m] = *reinterpret_cast<const bf16x8*>(&As[aoff[m]]);
        #pragma unroll
        for (int n = 0; n < 8; ++n)
            bf[n] = *reinterpret_cast<const bf16x8*>(&Bs[cur][boff[n]]);
        #pragma unroll
        for (int m = 0; m < 4; ++m)
            #pragma unroll
            for (int n = 0; n < 8; ++n)
                acc[m][n] = __builtin_amdgcn_mfma_f32_16x16x32_bf16(
                    af[m], bf[n], acc[m][n], 0, 0, 0);
    }

    // epilogue: sum over this lane's g of tanh(dp+c)*v
    float dpv[8], vv[8];
    #pragma unroll
    for (int n = 0; n < 8; ++n) {
        const int g = wn * 128 + n * 16 + gl;
        dpv[n] = dp[b * HID + g];
        vv[n]  = v[g];
    }
    float p[4][4];
    #pragma unroll
    for (int m = 0; m < 4; ++m)
        #pragma unroll
        for (int r = 0; r < 4; ++r) p[m][r] = 0.f;
    #pragma unroll
    for (int n = 0; n < 8; ++n)
        #pragma unroll
        for (int m = 0; m < 4; ++m)
            #pragma unroll
            for (int r = 0; r < 4; ++r)
                p[m][r] += fast_tanh(dpv[n] + acc[m][n][r]) * vv[n];

    #pragma unroll
    for (int m = 0; m < 4; ++m)
        #pragma unroll
        for (int r = 0; r < 4; ++r) {
            float x = p[m][r];
            x += __shfl_xor(x, 1);
            x += __shfl_xor(x, 2);
            x += __shfl_xor(x, 4);
            x += __shfl_xor(x, 8);
            p[m][r] = x;
        }
    if (gl == 0) {
        #pragma unroll
        for (int m = 0; m < 4; ++m)
            #pragma unroll
            for (int r = 0; r < 4; ++r)
                part[wv][m * 16 + rg * 4 + r] = p[m][r];
    }
    __syncthreads();

    if (t < 128) {
        const int row = t & 63, wmf = t >> 6;
        const float e = part[wmf * 4 + 0][row] + part[wmf * 4 + 1][row]
                      + part[wmf * 4 + 2][row] + part[wmf * 4 + 3][row];
        energy[(size_t)b * SEQ + s0 + t] = e;
    }
}

// ---------------------------------------------------------------------------
// K3: softmax over s per b, IN PLACE on the attn region of d_out.
// ---------------------------------------------------------------------------
__global__ void k_softmax(float* __restrict__ attn)
{
    __shared__ float redm[4], reds[4];
    const int b = blockIdx.x, t = threadIdx.x;
    float* e = attn + (size_t)b * SEQ;

    float4 ev[4];
    float m = -3.4e38f;
    #pragma unroll
    for (int i = 0; i < 4; ++i) {
        ev[i] = *reinterpret_cast<const float4*>(e + i * 1024 + t * 4);
        m = fmaxf(m, fmaxf(fmaxf(ev[i].x, ev[i].y), fmaxf(ev[i].z, ev[i].w)));
    }
    #pragma unroll
    for (int off = 1; off < 64; off <<= 1) m = fmaxf(m, __shfl_xor(m, off));
    if ((t & 63) == 0) redm[t >> 6] = m;
    __syncthreads();
    m = fmaxf(fmaxf(redm[0], redm[1]), fmaxf(redm[2], redm[3]));

    float s = 0.f;
    #pragma unroll
    for (int i = 0; i < 4; ++i) {
        ev[i].x = __expf(ev[i].x - m);  ev[i].y = __expf(ev[i].y - m);
        ev[i].z = __expf(ev[i].z - m);  ev[i].w = __expf(ev[i].w - m);
        s += (ev[i].x + ev[i].y) + (ev[i].z + ev[i].w);
    }
    #pragma unroll
    for (int off = 1; off < 64; off <<= 1) s += __shfl_xor(s, off);
    if ((t & 63) == 0) reds[t >> 6] = s;
    __syncthreads();
    s = (reds[0] + reds[1]) + (reds[2] + reds[3]);
    const float inv = 1.0f / s;

    #pragma unroll
    for (int i = 0; i < 4; ++i) {
        const float4 w4 = make_float4(ev[i].x * inv, ev[i].y * inv,
                                      ev[i].z * inv, ev[i].w * inv);
        *reinterpret_cast<float4*>(e + i * 1024 + t * 4) = w4;
    }
}

// ---------------------------------------------------------------------------
// K4: partial context. grid = (64 b, 16 s-splits), 256 threads.
// ---------------------------------------------------------------------------
__global__ void k_ctxpart(const float* __restrict__ enc,
                          const float* __restrict__ attn,
                          float* __restrict__ pctx)
{
    __shared__ float w[256];
    const int b  = blockIdx.x;
    const int sp = blockIdx.y;
    const int t  = threadIdx.x;

    w[t] = attn[(size_t)b * SEQ + sp * 256 + t];
    __syncthreads();

    const float2* e2 = reinterpret_cast<const float2*>(enc);
    size_t idx = ((size_t)sp * 256 * BATCH + b) * (HID / 2) + t;
    const size_t stride = (size_t)BATCH * (HID / 2);

    float ax = 0.f, ay = 0.f;
    #pragma unroll 4
    for (int s = 0; s < 256; ++s) {
        const float2 ev = e2[idx];
        const float ws = w[s];
        ax = fmaf(ws, ev.x, ax);
        ay = fmaf(ws, ev.y, ay);
        idx += stride;
    }
    float2* p2 = reinterpret_cast<float2*>(pctx);
    p2[((size_t)sp * BATCH + b) * (HID / 2) + t] = make_float2(ax, ay);
}

// ---------------------------------------------------------------------------
// K5: context[b][h] = sum over 16 splits.
// ---------------------------------------------------------------------------
__global__ void k_ctxsum(const float* __restrict__ pctx,
                         float* __restrict__ ctx)
{
    const int i = blockIdx.x * 256 + threadIdx.x;
    float s = 0.f;
    #pragma unroll
    for (int sp = 0; sp < 16; ++sp) s += pctx[(size_t)sp * BATCH * HID + i];
    ctx[i] = s;
}

// ---------------------------------------------------------------------------
extern "C" void kernel_launch(void* const* d_in, const int* in_sizes, int n_in,
                              void* d_out, int out_size, void* d_ws, size_t ws_size,
                              hipStream_t stream)
{
    const float* dh  = (const float*)d_in[0];
    const float* enc = (const float*)d_in[1];
    const float* W1  = (const float*)d_in[2];
    const float* W2  = (const float*)d_in[3];
    const float* v   = (const float*)d_in[4];

    float* out  = (float*)d_out;
    float* ctx  = out;                           // 64*512
    float* attn = out + BATCH * HID;             // 64*4096 (energy -> softmax in place)

    float*  dp   = (float*)d_ws;                 // 32768 f (128 KiB)
    ushort* W2t  = (ushort*)(dp + BATCH * HID);  // 262144 u16 (512 KiB)
    float*  pctx = (float*)(W2t + HID * HID);    // 16*64*512 f (2 MiB)

    k_cvtW2  <<<128, 256, 0, stream>>>(W2, W2t);
    k_decproj<<<HID, 256, 0, stream>>>(dh, W1, dp);
    k_energy <<<dim3(SEQ / 128, BATCH), 512, 0, stream>>>(enc, W2t, dp, v, attn);
    k_softmax<<<BATCH, 256, 0, stream>>>(attn);
    k_ctxpart<<<dim3(BATCH, 16), 256, 0, stream>>>(enc, attn, pctx);
    k_ctxsum <<<BATCH * HID / 256, 256, 0, stream>>>(pctx, ctx);
}